// Round 1
// baseline (261.101 us; speedup 1.0000x reference)
//
#include <hip/hip_runtime.h>

// Multi-threshold LIF accumulation.
// x: [T=4, B, N, C] fp32; thresholds: [4] fp32; out: [T, B, N, C] fp32.
// Each thread owns 4 consecutive channel elements (one float4) of one
// spatial position, loads all T=4 timestep values, runs the 4-threshold x
// 4-timestep LIF recurrence entirely in registers, writes 4 float4 outputs.
// Pure HBM-bandwidth kernel: 154 MB read + 154 MB write.

static constexpr int TT = 4;  // timesteps
static constexpr int JJ = 4;  // threshold blocks

__global__ __launch_bounds__(256) void lif_multithresh_kernel(
    const float4* __restrict__ x,
    const float* __restrict__ th,
    float4* __restrict__ out,
    int n4)  // float4s per timestep slab
{
    const int i = blockIdx.x * blockDim.x + threadIdx.x;
    if (i >= n4) return;

    // Load all timesteps for this position (coalesced float4 loads).
    float xv[TT][4];
#pragma unroll
    for (int t = 0; t < TT; ++t) {
        const float4 v = x[(size_t)t * (size_t)n4 + (size_t)i];
        xv[t][0] = v.x; xv[t][1] = v.y; xv[t][2] = v.z; xv[t][3] = v.w;
    }

    float thr[JJ];
#pragma unroll
    for (int j = 0; j < JJ; ++j) thr[j] = th[j];

    float acc[TT][4];
#pragma unroll
    for (int t = 0; t < TT; ++t)
#pragma unroll
        for (int c = 0; c < 4; ++c) acc[t][c] = 0.0f;

    // LIF: v = v + (x - v)/tau (tau = 2, exact /2), spike = (v >= th),
    // hard reset v = 0 on spike. Op order matches the reference exactly.
#pragma unroll
    for (int j = 0; j < JJ; ++j) {
        const float tj = thr[j];
#pragma unroll
        for (int c = 0; c < 4; ++c) {
            float v = 0.0f;
#pragma unroll
            for (int t = 0; t < TT; ++t) {
                v = v + (xv[t][c] - v) * 0.5f;
                const bool s = (v >= tj);
                acc[t][c] += s ? 1.0f : 0.0f;
                v = s ? 0.0f : v;
            }
        }
    }

#pragma unroll
    for (int t = 0; t < TT; ++t) {
        float4 o;
        o.x = acc[t][0]; o.y = acc[t][1]; o.z = acc[t][2]; o.w = acc[t][3];
        out[(size_t)t * (size_t)n4 + (size_t)i] = o;
    }
}

extern "C" void kernel_launch(void* const* d_in, const int* in_sizes, int n_in,
                              void* d_out, int out_size, void* d_ws, size_t ws_size,
                              hipStream_t stream) {
    const float* x  = (const float*)d_in[0];
    const float* th = (const float*)d_in[1];
    float* out = (float*)d_out;

    const int total = in_sizes[0];       // T*B*N*C
    const int S = total / TT;            // B*N*C per timestep
    const int n4 = S / 4;                // float4s per timestep (S % 4 == 0)

    const int block = 256;
    const int grid = (n4 + block - 1) / block;
    lif_multithresh_kernel<<<grid, block, 0, stream>>>(
        (const float4*)x, th, (float4*)out, n4);
}